// Round 8
// baseline (1013.001 us; speedup 1.0000x reference)
//
#include <hip/hip_runtime.h>
#include <hip/hip_bf16.h>

// MoE top-2-of-8 FFN + shared expert + router losses, MI355X gfx950.
// R5: router/scatter atomic de-serialization.
// R8: m97-canonical 128^2 single-buffer GEMM, 4 blocks/CU (best: 926us).
// R9/R10: launch_bounds(256,5) VGPR-spill disaster (rule: acc must fit the
//     per-wave budget the bound implies; hipcc spills silently).
// R11: BN=64 ev -> no change. KEY FINDING: MfmaUtil pinned ~28% in R8 & R11
//     with per-CU staged-bytes/window identical (~128KB) -> the K-loop is
//     bound by per-CU staging bandwidth, i.e. tile arithmetic intensity
//     (128^2/256rows = 64 flop/B), NOT by grid slots.
// R12: raise AI 1.33x: BM=256 x BN=128 x BK=64 8-wave (512thr) single-48KB-LDS
//     2-barrier body for sv/ek/ev (85 flop/B; 96KB staged per 2-block window
//     for 1.33x MFMA). VGPR ~120 -> 16 waves/CU = 2 blocks/CU. Grids:
//     ev 576, ek 2304 (90% util), sv 256. sk keeps 128^2 (2 exact rounds).
//     Segments pad to 256 (PERM_CAP 18432, MAX_TILES 72).

#define N_TOK 8192
#define DM    1024
#define HD    4096
#define NE    8
#define NKTOT 16384            // N_TOK * 2
#define PERM_CAP 18432         // NKTOT + NE*256 (segment padding to 256)
#define MAX_TILES 72           // sum ceil(T_e/256) <= NKTOT/256 + NE
#define RTOK_BLK 16            // router tokens per block

typedef __attribute__((ext_vector_type(8))) short bhalf8;
typedef __attribute__((ext_vector_type(8))) unsigned short ushort8v;
typedef __attribute__((ext_vector_type(4))) float floatx4;

__device__ __forceinline__ unsigned short f2bf(float f) {
  union { float f; unsigned int u; } v; v.f = f;
  unsigned int u = v.u;
  return (unsigned short)((u + 0x7fffu + ((u >> 16) & 1u)) >> 16);  // RNE
}

__device__ __forceinline__ float bf2f(unsigned short h) {
  union { unsigned int u; float f; } v; v.u = ((unsigned int)h) << 16;
  return v.f;
}

__device__ __forceinline__ float gelu_tanh(float h) {
  // jax.nn.gelu default (approximate=True)
  float u = 0.7978845608028654f * (h + 0.044715f * h * h * h);
  float t = 1.0f - 2.0f / (1.0f + __expf(2.0f * u));   // tanh(u)
  return 0.5f * h * (1.0f + t);
}

// global -> LDS direct DMA, 16B/lane. LDS dest is wave-uniform base + lane*16.
__device__ __forceinline__ void gload16(const unsigned short* g, void* l) {
  __builtin_amdgcn_global_load_lds(
      (const __attribute__((address_space(1))) void*)g,
      (__attribute__((address_space(3))) void*)l, 16, 0, 0);
}

// ---------------- init (ws is poisoned 0xAA each call) ----------------
__global__ void init_kernel(int* perm, float* permw, float* usage, float* zsum,
                            int* counts, int* fill) {
  int i = blockIdx.x * 256 + threadIdx.x;
  if (i < PERM_CAP) { perm[i] = 0; permw[i] = 0.0f; }
  if (i < NE) { usage[i] = 0.0f; counts[i] = 0; fill[i] = 0; }
  if (i == 0) zsum[0] = 0.0f;
}

// ---------------- x fp32 -> bf16 ----------------
__global__ void cvt_x_kernel(const float* __restrict__ x, unsigned short* __restrict__ xb) {
  size_t i = (size_t)(blockIdx.x * 256 + threadIdx.x) * 4;
  float4 v = *(const float4*)(x + i);
  ushort4 o;
  o.x = f2bf(v.x); o.y = f2bf(v.y); o.z = f2bf(v.z); o.w = f2bf(v.w);
  *(ushort4*)(xb + i) = o;
}

// ---------------- router: logits, top-2 softmax, aux-loss partials ----------------
__global__ void router_kernel(const float* __restrict__ x, const float* __restrict__ gw,
                              int* __restrict__ idxb, float* __restrict__ wbuf,
                              float* __restrict__ usage, float* __restrict__ zsum,
                              int* __restrict__ counts) {
  __shared__ float s_use[NE];
  __shared__ int   s_cnt[NE];
  __shared__ float s_z;
  int t = threadIdx.x;
  if (t < NE) { s_use[t] = 0.0f; s_cnt[t] = 0; }
  if (t == 0) s_z = 0.0f;
  __syncthreads();

  int wave = t >> 6;
  int lane = t & 63;

  float luse[NE]; int lcnt[NE];
#pragma unroll
  for (int e = 0; e < NE; e++) { luse[e] = 0.0f; lcnt[e] = 0; }
  float lz = 0.0f;

#pragma unroll
  for (int i = 0; i < 4; i++) {
    int n = blockIdx.x * RTOK_BLK + wave * 4 + i;
    const float* xr = x + (size_t)n * DM;
    float acc[NE];
#pragma unroll
    for (int e = 0; e < NE; e++) acc[e] = 0.0f;
    for (int d = lane; d < DM; d += 64) {
      float xv = xr[d];
      const float* g = gw + (size_t)d * NE;
#pragma unroll
      for (int e = 0; e < NE; e++) acc[e] += xv * g[e];
    }
#pragma unroll
    for (int e = 0; e < NE; e++) {
#pragma unroll
      for (int off = 32; off > 0; off >>= 1) acc[e] += __shfl_xor(acc[e], off);
    }
    if (lane == 0) {
      float m1 = acc[0]; int i1 = 0;
#pragma unroll
      for (int e = 1; e < NE; e++) if (acc[e] > m1) { m1 = acc[e]; i1 = e; }
      float m2 = -3.0e38f; int i2 = 0;
#pragma unroll
      for (int e = 0; e < NE; e++) if (e != i1 && acc[e] > m2) { m2 = acc[e]; i2 = e; }
      float e1 = __expf(m2 - m1);
      float w1 = 1.0f / (1.0f + e1);
      float w2 = e1 / (1.0f + e1);
      float s = 0.0f;
#pragma unroll
      for (int e = 0; e < NE; e++) s += __expf(acc[e] - m1);
      float lse = m1 + __logf(s);
      idxb[n * 2 + 0] = i1; idxb[n * 2 + 1] = i2;
      wbuf[n * 2 + 0] = w1; wbuf[n * 2 + 1] = w2;
      luse[i1] += w1; luse[i2] += w2;
      lcnt[i1]++;     lcnt[i2]++;
      lz += lse * lse;
    }
  }

  if (lane == 0) {
#pragma unroll
    for (int e = 0; e < NE; e++) {
      atomicAdd(&s_use[e], luse[e]);
      atomicAdd(&s_cnt[e], lcnt[e]);
    }
    atomicAdd(&s_z, lz);
  }
  __syncthreads();
  if (t < NE) {
    atomicAdd(&usage[t], s_use[t]);
    atomicAdd(&counts[t], s_cnt[t]);
  }
  if (t == 0) atomicAdd(zsum, s_z);
}

// ---------------- scan: padded segment offsets, tile table, router loss ----------------
__global__ void scan_kernel(const int* __restrict__ counts, int* __restrict__ poff,
                            int* __restrict__ tileE, int* __restrict__ tileR,
                            int* __restrict__ nTiles,
                            const float* __restrict__ usage, const float* __restrict__ zsum,
                            float* __restrict__ lossOut) {
  if (threadIdx.x == 0 && blockIdx.x == 0) {
    int run = 0, nt = 0;
    for (int e = 0; e < NE; e++) {
      poff[e] = run;
      int t = (counts[e] + 255) >> 8;
      for (int i = 0; i < t; i++) { tileE[nt] = e; tileR[nt] = run + i * 256; nt++; }
      run += t << 8;
    }
    *nTiles = nt;
    float mean = 0.0f;
    for (int e = 0; e < NE; e++) mean += usage[e];
    mean *= (1.0f / NE);
    float var = 0.0f;
    for (int e = 0; e < NE; e++) { float d = usage[e] - mean; var += d * d; }
    var *= (1.0f / NE);
    float bal = sqrtf(var) / mean * 0.01f;
    float z = (zsum[0] / (float)N_TOK) * 0.001f;
    lossOut[0] = bal + z;
  }
}

// ---------------- scatter tokens into per-expert segments ----------------
__global__ void scatter_kernel(const int* __restrict__ idxb, const float* __restrict__ wbuf,
                               const int* __restrict__ poff, int* __restrict__ fill,
                               int* __restrict__ perm, float* __restrict__ permw,
                               int* __restrict__ pos) {
  __shared__ int lcnt[NE];
  __shared__ int lbase[NE];
  int t = threadIdx.x;
  if (t < NE) lcnt[t] = 0;
  __syncthreads();
  int i = blockIdx.x * 256 + t;          // grid sized exactly: i < NKTOT
  int e = idxb[i];
  int r = atomicAdd(&lcnt[e], 1);        // LDS rank within block
  __syncthreads();
  if (t < NE) lbase[t] = atomicAdd(&fill[t], lcnt[t]);
  __syncthreads();
  int p = poff[e] + lbase[e] + r;
  perm[p] = i >> 1;
  permw[p] = wbuf[i];
  pos[i] = p;
}

// ---------------- transpose+convert: src fp32 [R][C] -> dst bf16 [C][R], batched ----------------
// dst writes vectorized: each lane stores ushort8 (16B). LDS read stride 65
// words -> 8 consecutive rows hit 8 distinct banks (conflict-free).
__global__ void transpose_cvt_kernel(const float* __restrict__ src,
                                     unsigned short* __restrict__ dst, int R, int C) {
  __shared__ float tile[64][65];
  size_t bo = (size_t)blockIdx.z * R * C;
  src += bo; dst += bo;
  int r0 = blockIdx.x * 64, c0 = blockIdx.y * 64;
  int c = threadIdx.x & 63, r = threadIdx.x >> 6;
#pragma unroll
  for (int i = 0; i < 16; i++)
    tile[r + i * 4][c] = src[(size_t)(r0 + r + i * 4) * C + c0 + c];
  __syncthreads();
  int u = threadIdx.x & 7;        // dst 8-col group (src row group)
  int ow = threadIdx.x >> 3;      // 0..31: dst row offset base
#pragma unroll
  for (int it = 0; it < 2; it++) {
    int oc = ow + it * 32;        // src col -> dst row offset
    ushort8v o;
#pragma unroll
    for (int j = 0; j < 8; j++) o[j] = f2bf(tile[u * 8 + j][oc]);
    *(ushort8v*)&dst[(size_t)(c0 + oc) * R + r0 + u * 8] = o;
  }
}

// ---------------- combine: out[t] += eout[pos0[t]] + eout[pos1[t]] ----------------
__global__ void combine_kernel(float* __restrict__ out,
                               const unsigned short* __restrict__ eout,
                               const int* __restrict__ pos) {
  int t = blockIdx.x;
  int d = threadIdx.x * 8;
  int p0 = pos[t * 2], p1 = pos[t * 2 + 1];
  float* o = out + (size_t)t * DM + d;
  const unsigned short* e0 = eout + (size_t)p0 * DM + d;
  const unsigned short* e1 = eout + (size_t)p1 * DM + d;
  float4 a = *(const float4*)(o);
  float4 b = *(const float4*)(o + 4);
  ushort4 u0a = *(const ushort4*)(e0), u0b = *(const ushort4*)(e0 + 4);
  ushort4 u1a = *(const ushort4*)(e1), u1b = *(const ushort4*)(e1 + 4);
  a.x += bf2f(u0a.x) + bf2f(u1a.x);
  a.y += bf2f(u0a.y) + bf2f(u1a.y);
  a.z += bf2f(u0a.z) + bf2f(u1a.z);
  a.w += bf2f(u0a.w) + bf2f(u1a.w);
  b.x += bf2f(u0b.x) + bf2f(u1b.x);
  b.y += bf2f(u0b.y) + bf2f(u1b.y);
  b.z += bf2f(u0b.z) + bf2f(u1b.z);
  b.w += bf2f(u0b.w) + bf2f(u1b.w);
  *(float4*)(o) = a;
  *(float4*)(o + 4) = b;
}

// ---------------- shared_keys: 128x128xBK64, 4 waves, 32KB LDS (R8 body) ----------------
__global__ __launch_bounds__(256, 4) void gemm_shared_keys(
    const unsigned short* __restrict__ A, const unsigned short* __restrict__ BT,
    const float* __restrict__ bias, unsigned short* __restrict__ outH, int Kd, int Nd) {
  __shared__ __align__(16) unsigned short As[128 * 64];
  __shared__ __align__(16) unsigned short Bs[128 * 64];

  int id = blockIdx.x;
  int xcd = id & 7, q = id >> 3;
  int mt = xcd * 8 + (q & 7);      // band 8m, m-fastest: pin A-band + B-slab in L2
  int ntile = q >> 3;
  int n0 = ntile * 128, m0 = mt * 128;

  int t = threadIdx.x;
  int rsub = t >> 3;               // 0..31
  int gc = (t & 7) ^ (rsub & 7);   // swizzled global 16B-chunk index
  const unsigned short* aptr[4];
  const unsigned short* bptr[4];
#pragma unroll
  for (int p = 0; p < 4; p++) {
    int r = rsub + p * 32;
    aptr[p] = A + (size_t)(m0 + r) * Kd + gc * 8;
    bptr[p] = BT + (size_t)(n0 + r) * Kd + gc * 8;
  }
  char* ldsA = (char*)As + (t & 192) * 16;
  char* ldsB = (char*)Bs + (t & 192) * 16;

  int lane = t & 63;
  int wv = t >> 6;
  int wm = (wv >> 1) * 64, wn = (wv & 1) * 64;
  int lr = lane & 15, lq = lane >> 4;
  int rx = lr & 7;

  floatx4 acc[4][4];
#pragma unroll
  for (int i = 0; i < 4; i++)
#pragma unroll
    for (int j = 0; j < 4; j++) acc[i][j] = (floatx4){0.f, 0.f, 0.f, 0.f};

  for (int k0 = 0; k0 < Kd; k0 += 64) {
#pragma unroll
    for (int p = 0; p < 4; p++) {
      gload16(aptr[p] + k0, ldsA + p * 4096);
      gload16(bptr[p] + k0, ldsB + p * 4096);
    }
    __syncthreads();
#pragma unroll
    for (int kk = 0; kk < 2; kk++) {
      int ca = kk * 4 + lq;
      bhalf8 af[4], bf[4];
#pragma unroll
      for (int i = 0; i < 4; i++) {
        af[i] = *(const bhalf8*)&As[(wm + i * 16 + lr) * 64 + ((ca ^ rx) * 8)];
        bf[i] = *(const bhalf8*)&Bs[(wn + i * 16 + lr) * 64 + ((ca ^ rx) * 8)];
      }
#pragma unroll
      for (int mtile = 0; mtile < 4; mtile++)
#pragma unroll
        for (int ntl = 0; ntl < 4; ntl++)
          acc[mtile][ntl] = __builtin_amdgcn_mfma_f32_16x16x32_bf16(af[mtile], bf[ntl], acc[mtile][ntl], 0, 0, 0);
    }
    __syncthreads();
  }

#pragma unroll
  for (int mtile = 0; mtile < 4; mtile++) {
#pragma unroll
    for (int ntl = 0; ntl < 4; ntl++) {
      int ncol = n0 + wn + ntl * 16 + lr;
      float bb = bias[ncol];
#pragma unroll
      for (int r = 0; r < 4; r++) {
        int mrow = wm + mtile * 16 + lq * 4 + r;
        float v = acc[mtile][ntl][r] + bb;
        outH[(size_t)(m0 + mrow) * Nd + ncol] = f2bf(gelu_tanh(v));
      }
    }
  }
}

// ---------------- 256x128xBK64, 8 waves (512thr), single 48KB LDS, 2-barrier ----------------
// AI = 85 flop/staged-byte (vs 64 at 128^2). VGPR ~120 -> 16 waves/CU =
// 2 blocks/CU; per-window staged bytes 96KB for 1.33x the MFMA of the 128^2
// body. Same pre-swizzled-source + XOR-read LDS scheme (bank-conflict 0).
// MODE 1 = shared_values (f32 out), 2 = expert_keys (perm-gathered A, gelu
// bf16 out), 3 = expert_values (weighted bf16 out).
template<int MODE>
__device__ __forceinline__ void gemm_body_512(
    const unsigned short* __restrict__ A,
    const unsigned short* __restrict__ BT,
    const float* __restrict__ bias,
    float* __restrict__ outF,
    unsigned short* __restrict__ outH,
    int Kd, int Nd,
    const int* __restrict__ perm,
    const float* __restrict__ permw,
    const int* __restrict__ tileE,
    const int* __restrict__ tileR,
    const int* __restrict__ nTiles) {
  __shared__ __align__(16) unsigned short As[256 * 64];   // 32 KB
  __shared__ __align__(16) unsigned short Bs[128 * 64];   // 16 KB

  int id = blockIdx.x;
  int xcd = id & 7, q = id >> 3;
  int mt, ntile;
  if (MODE == 1)      { mt = xcd * 4 + (q & 3);  ntile = q >> 2; }  // 256 blk: 32m x 8n
  else if (MODE == 2) { mt = xcd * 9 + (q >> 5); ntile = q & 31; }  // 2304 blk: 72m x 32n
  else                { mt = xcd * 9 + (q >> 3); ntile = q & 7;  }  // 576 blk: 72m x 8n

  int n0 = ntile * 128;
  int prow0 = 0, m0 = 0;
  if (MODE >= 2) {
    if (mt >= *nTiles) return;
    int e = tileE[mt];
    prow0 = tileR[mt];
    BT += (size_t)e * Kd * Nd;
    bias += (size_t)e * Nd;
  } else {
    m0 = mt * 256;
  }

  int t = threadIdx.x;
  int wid = t >> 6, lane = t & 63;
  int rsub = t >> 3;                // 0..63: row within a 64-row staging call
  int gc = (t & 7) ^ (rsub & 7);    // swizzled global 16B-chunk index
  const unsigned short* aptr[4];    // A rows c*64+rsub
  const unsigned short* bptr[2];    // B rows c*64+rsub
#pragma unroll
  for (int c = 0; c < 4; c++) {
    int r = c * 64 + rsub;
    size_t grow;
    if (MODE == 2)      grow = (size_t)perm[prow0 + r];
    else if (MODE == 3) grow = (size_t)(prow0 + r);
    else                grow = (size_t)(m0 + r);
    aptr[c] = A + grow * Kd + gc * 8;
  }
#pragma unroll
  for (int c = 0; c < 2; c++)
    bptr[c] = BT + (size_t)(n0 + c * 64 + rsub) * Kd + gc * 8;

  // wave-uniform LDS staging bases (HW adds lane*16); call c -> +c*8192 B
  char* ldsA = (char*)As + wid * 1024;
  char* ldsB = (char*)Bs + wid * 1024;

  int wr = wid >> 1, wc = wid & 1;          // wave tile: rows wr*64, cols wc*64
  int lr = lane & 15, lq = lane >> 4;
  int rx = lr & 7;

  floatx4 acc[4][4];
#pragma unroll
  for (int i = 0; i < 4; i++)
#pragma unroll
    for (int j = 0; j < 4; j++) acc[i][j] = (floatx4){0.f, 0.f, 0.f, 0.f};

  for (int k0 = 0; k0 < Kd; k0 += 64) {
#pragma unroll
    for (int c = 0; c < 4; c++) gload16(aptr[c] + k0, ldsA + c * 8192);
#pragma unroll
    for (int c = 0; c < 2; c++) gload16(bptr[c] + k0, ldsB + c * 8192);
    __syncthreads();               // drains vmcnt(0): tile staged
#pragma unroll
    for (int kk = 0; kk < 2; kk++) {
      int ca = kk * 4 + lq;
      bhalf8 af[4], bf[4];
#pragma unroll
      for (int i = 0; i < 4; i++)
        af[i] = *(const bhalf8*)&As[(wr * 64 + i * 16 + lr) * 64 + ((ca ^ rx) * 8)];
#pragma unroll
      for (int j = 0; j < 4; j++)
        bf[j] = *(const bhalf8*)&Bs[(wc * 64 + j * 16 + lr) * 64 + ((ca ^ rx) * 8)];
#pragma unroll
      for (int i = 0; i < 4; i++)
#pragma unroll
        for (int j = 0; j < 4; j++)
          acc[i][j] = __builtin_amdgcn_mfma_f32_16x16x32_bf16(af[i], bf[j], acc[i][j], 0, 0, 0);
    }
    __syncthreads();               // protect buffer before next stage
  }

  // epilogue: frag D[row=lq*4+r][col=lr]
#pragma unroll
  for (int j = 0; j < 4; j++) {
    int ncol = n0 + wc * 64 + j * 16 + lr;
    float bb = bias[ncol];
#pragma unroll
    for (int i = 0; i < 4; i++) {
#pragma unroll
      for (int r = 0; r < 4; r++) {
        int mrow = wr * 64 + i * 16 + lq * 4 + r;       // local row 0..255
        float v = acc[i][j][r] + bb;
        if (MODE == 1) {
          outF[(size_t)(m0 + mrow) * Nd + ncol] = v;
        } else if (MODE == 2) {
          outH[(size_t)(prow0 + mrow) * Nd + ncol] = f2bf(gelu_tanh(v));
        } else {
          int prow = prow0 + mrow;
          float w = permw[prow];
          outH[(size_t)prow * Nd + ncol] = f2bf(w * v);   // weighted expert out
        }
      }
    }
  }
}

__global__ __launch_bounds__(512, 4) void gemm_shared_values(
    const unsigned short* A, const unsigned short* BT, const float* bias,
    float* outF, unsigned short* outH, int Kd, int Nd,
    const int* perm, const float* permw, const int* tE, const int* tR, const int* nT) {
  gemm_body_512<1>(A, BT, bias, outF, outH, Kd, Nd, perm, permw, tE, tR, nT);
}
__global__ __launch_bounds__(512, 4) void gemm_expert_keys(
    const unsigned short* A, const unsigned short* BT, const float* bias,
    float* outF, unsigned short* outH, int Kd, int Nd,
    const int* perm, const float* permw, const int* tE, const int* tR, const int* nT) {
  gemm_body_512<2>(A, BT, bias, outF, outH, Kd, Nd, perm, permw, tE, tR, nT);
}
__global__ __launch_bounds__(512, 4) void gemm_expert_values(
    const unsigned short* A, const unsigned short* BT, const float* bias,
    float* outF, unsigned short* outH, int Kd, int Nd,
    const int* perm, const float* permw, const int* tE, const int* tR, const int* nT) {
  gemm_body_512<3>(A, BT, bias, outF, outH, Kd, Nd, perm, permw, tE, tR, nT);
}

extern "C" void kernel_launch(void* const* d_in, const int* in_sizes, int n_in,
                              void* d_out, int out_size, void* d_ws, size_t ws_size,
                              hipStream_t stream) {
  const float* x        = (const float*)d_in[0];
  const float* gate_w   = (const float*)d_in[1];
  const float* keys_w   = (const float*)d_in[2];
  const float* keys_b   = (const float*)d_in[3];
  const float* values_w = (const float*)d_in[4];
  const float* values_b = (const float*)d_in[5];
  const float* sk_w     = (const float*)d_in[6];
  const float* sk_b     = (const float*)d_in[7];
  const float* sv_w     = (const float*)d_in[8];
  const float* sv_b     = (const float*)d_in[9];
  float* out = (float*)d_out;

  char* p = (char*)d_ws;
  unsigned short* xb   = (unsigned short*)p; p += (size_t)N_TOK * DM * 2;     // 16 MB
  unsigned short* wt   = (unsigned short*)p; p += (size_t)NE * DM * HD * 2;   // 64 MB (phased)
  unsigned short* hid  = (unsigned short*)p; p += (size_t)PERM_CAP * HD * 2;  // 151 MB
  unsigned short* eout = (unsigned short*)p; p += (size_t)PERM_CAP * DM * 2;  // 37.8 MB
  int*   idxb   = (int*)p;   p += NKTOT * 4;
  float* wbuf   = (float*)p; p += NKTOT * 4;
  int*   perm   = (int*)p;   p += PERM_CAP * 4;
  float* permw  = (float*)p; p += PERM_CAP * 4;
  int*   pos    = (int*)p;   p += NKTOT * 4;
  int*   counts = (int*)p;   p += NE * 4;
  int*   fill   = (int*)p;   p += NE * 4;
  int*   poff   = (int*)p;   p += NE * 4;
  float* usage  = (float*)p; p += NE * 4;
  float* zsum   = (float*)p; p += 16;
  int*   tileE  = (int*)p;   p += MAX_TILES * 4;
  int*   tileR  = (int*)p;   p += MAX_TILES * 4;
  int*   nTiles = (int*)p;   p += 16;

  float* lossOut = out + (size_t)N_TOK * DM;

  // 1) init + convert + router
  init_kernel<<<(PERM_CAP + 255) / 256, 256, 0, stream>>>(perm, permw, usage, zsum, counts, fill);
  cvt_x_kernel<<<(N_TOK * DM / 4 + 255) / 256, 256, 0, stream>>>(x, xb);
  router_kernel<<<N_TOK / RTOK_BLK, 256, 0, stream>>>(x, gate_w, idxb, wbuf, usage, zsum, counts);
  scan_kernel<<<1, 64, 0, stream>>>(counts, poff, tileE, tileR, nTiles, usage, zsum, lossOut);
  scatter_kernel<<<NKTOT / 256, 256, 0, stream>>>(idxb, wbuf, poff, fill, perm, permw, pos);

  // 2) shared expert: hid = gelu(x @ Wk + b); out = hid @ Wv + b
  transpose_cvt_kernel<<<dim3(DM / 64, HD / 64, 1), 256, 0, stream>>>(sk_w, wt, DM, HD);
  gemm_shared_keys<<<2048, 256, 0, stream>>>(             // 128^2 body: 2 exact rounds
      xb, wt, sk_b, hid, DM, HD);
  transpose_cvt_kernel<<<dim3(HD / 64, DM / 64, 1), 256, 0, stream>>>(sv_w, wt, HD, DM);
  gemm_shared_values<<<256, 512, 0, stream>>>(            // 8 xcd * 4 m * 8 n (1/CU)
      hid, wt, sv_b, out, nullptr, HD, DM, perm, permw, tileE, tileR, nTiles);

  // 3) routed experts (grouped, sparse top-2)
  transpose_cvt_kernel<<<dim3(DM / 64, HD / 64, NE), 256, 0, stream>>>(keys_w, wt, DM, HD);
  gemm_expert_keys<<<2304, 512, 0, stream>>>(             // 8 xcd * 9 m * 32 n
      xb, wt, keys_b, nullptr, hid, DM, HD, perm, permw, tileE, tileR, nTiles);
  transpose_cvt_kernel<<<dim3(HD / 64, DM / 64, NE), 256, 0, stream>>>(values_w, wt, HD, DM);
  gemm_expert_values<<<576, 512, 0, stream>>>(            // 8 xcd * 9 m * 8 n
      hid, wt, values_b, nullptr, eout, HD, DM, perm, permw, tileE, tileR, nTiles);

  // 4) out += top-2 expert contributions
  combine_kernel<<<N_TOK, 128, 0, stream>>>(out, eout, pos);
}

// Round 9
// 935.022 us; speedup vs baseline: 1.0834x; 1.0834x over previous
//
#include <hip/hip_runtime.h>
#include <hip/hip_bf16.h>

// MoE top-2-of-8 FFN + shared expert + router losses, MI355X gfx950.
// R8: m97-canonical 128^2 single-buffer GEMM, 4 blocks/CU (926us best).
// R9/R10: (256,5) spills: body needs 128 unified regs (64 VGPR + 64 AGPR),
//     5 waves/SIMD allows 102. R11 (BN=64) & R12 (BM=256): both ~equal-or-
//     worse; per-CU throughput ~constant (~1300 TF chip) for 2-barrier bodies
//     at >=4 resident wave-groups -> only lever left is SLOT UTILIZATION.
// R13: merge sv+ev into ONE values GEMM ("expert 8" = shared):
//     - sk writes hidden into hid rows [PERM_CAP, PERM_CAP+8192)
//     - scan appends 64 shared tiles (e=8); nTiles[0]=expert, [1]=total
//     - wt = 9 slots (values_w^T 0..7 + sv_w^T at 8)
//     - merged epilogue (block-uniform branch): e<8 -> weighted bf16 eout;
//       e==8 -> f32 out (+sv bias)
//     sv(512 items, half-idle, ~65us) + ev(1088 items, 2 rounds 53%, 210us)
//     -> 1600 items, 2 rounds at 78% util ~= 215us. ushort8 transposes kept.

#define N_TOK 8192
#define DM    1024
#define HD    4096
#define NE    8
#define NKTOT 16384            // N_TOK * 2
#define PERM_CAP 17408         // NKTOT + NE*128 (segment padding)
#define SH_TILES 64            // shared-expert m-tiles (8192/128)
#define MAX_TILES 200          // 136 expert + 64 shared
#define BAND 17                // expert tiles / 8 xcds
#define BANDV 25               // (136+64) / 8 xcds
#define RTOK_BLK 16            // router tokens per block

typedef __attribute__((ext_vector_type(8))) short bhalf8;
typedef __attribute__((ext_vector_type(8))) unsigned short ushort8v;
typedef __attribute__((ext_vector_type(4))) float floatx4;

__device__ __forceinline__ unsigned short f2bf(float f) {
  union { float f; unsigned int u; } v; v.f = f;
  unsigned int u = v.u;
  return (unsigned short)((u + 0x7fffu + ((u >> 16) & 1u)) >> 16);  // RNE
}

__device__ __forceinline__ float bf2f(unsigned short h) {
  union { unsigned int u; float f; } v; v.u = ((unsigned int)h) << 16;
  return v.f;
}

__device__ __forceinline__ float gelu_tanh(float h) {
  // jax.nn.gelu default (approximate=True)
  float u = 0.7978845608028654f * (h + 0.044715f * h * h * h);
  float t = 1.0f - 2.0f / (1.0f + __expf(2.0f * u));   // tanh(u)
  return 0.5f * h * (1.0f + t);
}

// global -> LDS direct DMA, 16B/lane. LDS dest is wave-uniform base + lane*16.
__device__ __forceinline__ void gload16(const unsigned short* g, void* l) {
  __builtin_amdgcn_global_load_lds(
      (const __attribute__((address_space(1))) void*)g,
      (__attribute__((address_space(3))) void*)l, 16, 0, 0);
}

// ---------------- init (ws is poisoned 0xAA each call) ----------------
__global__ void init_kernel(int* perm, float* permw, float* usage, float* zsum,
                            int* counts, int* fill) {
  int i = blockIdx.x * 256 + threadIdx.x;
  if (i < PERM_CAP) { perm[i] = 0; permw[i] = 0.0f; }
  if (i < NE) { usage[i] = 0.0f; counts[i] = 0; fill[i] = 0; }
  if (i == 0) zsum[0] = 0.0f;
}

// ---------------- x fp32 -> bf16 ----------------
__global__ void cvt_x_kernel(const float* __restrict__ x, unsigned short* __restrict__ xb) {
  size_t i = (size_t)(blockIdx.x * 256 + threadIdx.x) * 4;
  float4 v = *(const float4*)(x + i);
  ushort4 o;
  o.x = f2bf(v.x); o.y = f2bf(v.y); o.z = f2bf(v.z); o.w = f2bf(v.w);
  *(ushort4*)(xb + i) = o;
}

// ---------------- router: logits, top-2 softmax, aux-loss partials ----------------
__global__ void router_kernel(const float* __restrict__ x, const float* __restrict__ gw,
                              int* __restrict__ idxb, float* __restrict__ wbuf,
                              float* __restrict__ usage, float* __restrict__ zsum,
                              int* __restrict__ counts) {
  __shared__ float s_use[NE];
  __shared__ int   s_cnt[NE];
  __shared__ float s_z;
  int t = threadIdx.x;
  if (t < NE) { s_use[t] = 0.0f; s_cnt[t] = 0; }
  if (t == 0) s_z = 0.0f;
  __syncthreads();

  int wave = t >> 6;
  int lane = t & 63;

  float luse[NE]; int lcnt[NE];
#pragma unroll
  for (int e = 0; e < NE; e++) { luse[e] = 0.0f; lcnt[e] = 0; }
  float lz = 0.0f;

#pragma unroll
  for (int i = 0; i < 4; i++) {
    int n = blockIdx.x * RTOK_BLK + wave * 4 + i;
    const float* xr = x + (size_t)n * DM;
    float acc[NE];
#pragma unroll
    for (int e = 0; e < NE; e++) acc[e] = 0.0f;
    for (int d = lane; d < DM; d += 64) {
      float xv = xr[d];
      const float* g = gw + (size_t)d * NE;
#pragma unroll
      for (int e = 0; e < NE; e++) acc[e] += xv * g[e];
    }
#pragma unroll
    for (int e = 0; e < NE; e++) {
#pragma unroll
      for (int off = 32; off > 0; off >>= 1) acc[e] += __shfl_xor(acc[e], off);
    }
    if (lane == 0) {
      float m1 = acc[0]; int i1 = 0;
#pragma unroll
      for (int e = 1; e < NE; e++) if (acc[e] > m1) { m1 = acc[e]; i1 = e; }
      float m2 = -3.0e38f; int i2 = 0;
#pragma unroll
      for (int e = 0; e < NE; e++) if (e != i1 && acc[e] > m2) { m2 = acc[e]; i2 = e; }
      float e1 = __expf(m2 - m1);
      float w1 = 1.0f / (1.0f + e1);
      float w2 = e1 / (1.0f + e1);
      float s = 0.0f;
#pragma unroll
      for (int e = 0; e < NE; e++) s += __expf(acc[e] - m1);
      float lse = m1 + __logf(s);
      idxb[n * 2 + 0] = i1; idxb[n * 2 + 1] = i2;
      wbuf[n * 2 + 0] = w1; wbuf[n * 2 + 1] = w2;
      luse[i1] += w1; luse[i2] += w2;
      lcnt[i1]++;     lcnt[i2]++;
      lz += lse * lse;
    }
  }

  if (lane == 0) {
#pragma unroll
    for (int e = 0; e < NE; e++) {
      atomicAdd(&s_use[e], luse[e]);
      atomicAdd(&s_cnt[e], lcnt[e]);
    }
    atomicAdd(&s_z, lz);
  }
  __syncthreads();
  if (t < NE) {
    atomicAdd(&usage[t], s_use[t]);
    atomicAdd(&counts[t], s_cnt[t]);
  }
  if (t == 0) atomicAdd(zsum, s_z);
}

// ---------------- scan: padded segment offsets, tile table, router loss ----------------
__global__ void scan_kernel(const int* __restrict__ counts, int* __restrict__ poff,
                            int* __restrict__ tileE, int* __restrict__ tileR,
                            int* __restrict__ nTiles,
                            const float* __restrict__ usage, const float* __restrict__ zsum,
                            float* __restrict__ lossOut) {
  if (threadIdx.x == 0 && blockIdx.x == 0) {
    int run = 0, nt = 0;
    for (int e = 0; e < NE; e++) {
      poff[e] = run;
      int t = (counts[e] + 127) >> 7;
      for (int i = 0; i < t; i++) { tileE[nt] = e; tileR[nt] = run + i * 128; nt++; }
      run += t << 7;
    }
    nTiles[0] = nt;                       // expert tiles (for keys GEMM)
    for (int i = 0; i < SH_TILES; i++) {  // shared-expert tiles (values GEMM)
      tileE[nt + i] = NE;                 // e = 8 -> shared
      tileR[nt + i] = PERM_CAP + i * 128; // hid shared region rows
    }
    nTiles[1] = nt + SH_TILES;            // total tiles (for values GEMM)
    float mean = 0.0f;
    for (int e = 0; e < NE; e++) mean += usage[e];
    mean *= (1.0f / NE);
    float var = 0.0f;
    for (int e = 0; e < NE; e++) { float d = usage[e] - mean; var += d * d; }
    var *= (1.0f / NE);
    float bal = sqrtf(var) / mean * 0.01f;
    float z = (zsum[0] / (float)N_TOK) * 0.001f;
    lossOut[0] = bal + z;
  }
}

// ---------------- scatter tokens into per-expert segments ----------------
__global__ void scatter_kernel(const int* __restrict__ idxb, const float* __restrict__ wbuf,
                               const int* __restrict__ poff, int* __restrict__ fill,
                               int* __restrict__ perm, float* __restrict__ permw,
                               int* __restrict__ pos) {
  __shared__ int lcnt[NE];
  __shared__ int lbase[NE];
  int t = threadIdx.x;
  if (t < NE) lcnt[t] = 0;
  __syncthreads();
  int i = blockIdx.x * 256 + t;          // grid sized exactly: i < NKTOT
  int e = idxb[i];
  int r = atomicAdd(&lcnt[e], 1);        // LDS rank within block
  __syncthreads();
  if (t < NE) lbase[t] = atomicAdd(&fill[t], lcnt[t]);
  __syncthreads();
  int p = poff[e] + lbase[e] + r;
  perm[p] = i >> 1;
  permw[p] = wbuf[i];
  pos[i] = p;
}

// ---------------- transpose+convert: src fp32 [R][C] -> dst bf16 [C][R], batched ----------------
// dst writes vectorized: each lane stores ushort8 (16B). LDS read stride 65
// words -> 8 consecutive rows hit 8 distinct banks (conflict-free).
__global__ void transpose_cvt_kernel(const float* __restrict__ src,
                                     unsigned short* __restrict__ dst, int R, int C) {
  __shared__ float tile[64][65];
  size_t bo = (size_t)blockIdx.z * R * C;
  src += bo; dst += bo;
  int r0 = blockIdx.x * 64, c0 = blockIdx.y * 64;
  int c = threadIdx.x & 63, r = threadIdx.x >> 6;
#pragma unroll
  for (int i = 0; i < 16; i++)
    tile[r + i * 4][c] = src[(size_t)(r0 + r + i * 4) * C + c0 + c];
  __syncthreads();
  int u = threadIdx.x & 7;        // dst 8-col group (src row group)
  int ow = threadIdx.x >> 3;      // 0..31: dst row offset base
#pragma unroll
  for (int it = 0; it < 2; it++) {
    int oc = ow + it * 32;        // src col -> dst row offset
    ushort8v o;
#pragma unroll
    for (int j = 0; j < 8; j++) o[j] = f2bf(tile[u * 8 + j][oc]);
    *(ushort8v*)&dst[(size_t)(c0 + oc) * R + r0 + u * 8] = o;
  }
}

// ---------------- combine: out[t] += eout[pos0[t]] + eout[pos1[t]] ----------------
__global__ void combine_kernel(float* __restrict__ out,
                               const unsigned short* __restrict__ eout,
                               const int* __restrict__ pos) {
  int t = blockIdx.x;
  int d = threadIdx.x * 8;
  int p0 = pos[t * 2], p1 = pos[t * 2 + 1];
  float* o = out + (size_t)t * DM + d;
  const unsigned short* e0 = eout + (size_t)p0 * DM + d;
  const unsigned short* e1 = eout + (size_t)p1 * DM + d;
  float4 a = *(const float4*)(o);
  float4 b = *(const float4*)(o + 4);
  ushort4 u0a = *(const ushort4*)(e0), u0b = *(const ushort4*)(e0 + 4);
  ushort4 u1a = *(const ushort4*)(e1), u1b = *(const ushort4*)(e1 + 4);
  a.x += bf2f(u0a.x) + bf2f(u1a.x);
  a.y += bf2f(u0a.y) + bf2f(u1a.y);
  a.z += bf2f(u0a.z) + bf2f(u1a.z);
  a.w += bf2f(u0a.w) + bf2f(u1a.w);
  b.x += bf2f(u0b.x) + bf2f(u1b.x);
  b.y += bf2f(u0b.y) + bf2f(u1b.y);
  b.z += bf2f(u0b.z) + bf2f(u1b.z);
  b.w += bf2f(u0b.w) + bf2f(u1b.w);
  *(float4*)(o) = a;
  *(float4*)(o + 4) = b;
}

// ---------------- 128x128xBK64 bf16 MFMA GEMM, m97-canonical single buffer ----------------
// 256 threads = 4 waves (2x2 of 64x64 wave tiles). LDS 32KB, 4 blocks/CU
// (128 unified regs/thread = the cliff; do NOT add K-loop-live registers).
// MODE 0 = shared_keys (dense rows, gelu bf16 out)
// MODE 2 = expert_keys (perm-gathered rows, gelu bf16 out, bound nT[0])
// MODE 4 = merged values (direct rows; e<8 weighted bf16 eout, e==8 f32 out;
//          bound nT[1]; bias2 = sv_b)
template<int MODE>
__device__ __forceinline__ void gemm_body(
    const unsigned short* __restrict__ A,
    const unsigned short* __restrict__ BT,
    const float* __restrict__ bias,
    const float* __restrict__ bias2,
    float* __restrict__ outF,
    unsigned short* __restrict__ outH,
    int Kd, int Nd,
    const int* __restrict__ perm,
    const float* __restrict__ permw,
    const int* __restrict__ tileE,
    const int* __restrict__ tileR,
    const int* __restrict__ nTiles) {
  __shared__ __align__(16) unsigned short As[128 * 64];
  __shared__ __align__(16) unsigned short Bs[128 * 64];

  int id = blockIdx.x;
  int xcd = id & 7, q = id >> 3;
  int mt, ntile;
  if (MODE == 0) {              // band 8m, m-fastest: pin A-band + B-slab in L2
    mt = xcd * 8 + (q & 7);
    ntile = q >> 3;
  } else if (MODE == 2) {       // band 17m, supertile 4m x 8n
    int n_in = q & 7, m_in = (q >> 3) & 3, ng = (q >> 5) & 3, mg = q >> 7;
    int mband = mg * 4 + m_in;
    if (mband >= BAND) return;
    mt = xcd * BAND + mband;
    ntile = ng * 8 + n_in;
  } else {                      // MODE 4: band 25m, n-fastest per m (pin A panel)
    mt = xcd * BANDV + (q >> 3);
    ntile = q & 7;
  }

  int n0 = ntile * 128;
  int prow0 = 0, m0 = 0, e = 0;
  if (MODE == 2) {
    if (mt >= nTiles[0]) return;
    e = tileE[mt];
    prow0 = tileR[mt];
    BT += (size_t)e * Kd * Nd;
    bias += (size_t)e * Nd;
  } else if (MODE == 4) {
    if (mt >= nTiles[1]) return;
    e = tileE[mt];
    prow0 = tileR[mt];
    BT += (size_t)e * Kd * Nd;             // wt has 9 slots; e=8 -> sv_w^T
    bias = (e < NE) ? bias + (size_t)e * Nd : bias2;
  } else {
    m0 = mt * 128;
  }

  int t = threadIdx.x;
  int rsub = t >> 3;               // 0..31: row within 32-row staging slab
  int gc = (t & 7) ^ (rsub & 7);   // swizzled global 16B-chunk index
  const unsigned short* aptr[4];
  const unsigned short* bptr[4];
#pragma unroll
  for (int p = 0; p < 4; p++) {
    int r = rsub + p * 32;
    size_t grow;
    if (MODE == 2)      grow = (size_t)perm[prow0 + r];
    else if (MODE == 4) grow = (size_t)(prow0 + r);
    else                grow = (size_t)(m0 + r);
    aptr[p] = A + grow * Kd + gc * 8;
    bptr[p] = BT + (size_t)(n0 + r) * Kd + gc * 8;
  }
  // wave-uniform LDS staging bases (lane*16 is added by HW)
  char* ldsA = (char*)As + (t & 192) * 16;
  char* ldsB = (char*)Bs + (t & 192) * 16;

  int lane = t & 63;
  int wv = t >> 6;
  int wm = (wv >> 1) * 64, wn = (wv & 1) * 64;
  int lr = lane & 15, lq = lane >> 4;
  int rx = lr & 7;                  // read-side row XOR key

  floatx4 acc[4][4];
#pragma unroll
  for (int i = 0; i < 4; i++)
#pragma unroll
    for (int j = 0; j < 4; j++) acc[i][j] = (floatx4){0.f, 0.f, 0.f, 0.f};

  for (int k0 = 0; k0 < Kd; k0 += 64) {
#pragma unroll
    for (int p = 0; p < 4; p++) {
      gload16(aptr[p] + k0, ldsA + p * 4096);
      gload16(bptr[p] + k0, ldsB + p * 4096);
    }
    __syncthreads();               // drains vmcnt(0): tile staged
#pragma unroll
    for (int kk = 0; kk < 2; kk++) {       // two 16x16x32 k-steps
      int ca = kk * 4 + lq;                // global chunk for this frag
      bhalf8 af[4], bf[4];
#pragma unroll
      for (int i = 0; i < 4; i++) {
        af[i] = *(const bhalf8*)&As[(wm + i * 16 + lr) * 64 + ((ca ^ rx) * 8)];
        bf[i] = *(const bhalf8*)&Bs[(wn + i * 16 + lr) * 64 + ((ca ^ rx) * 8)];
      }
#pragma unroll
      for (int mtile = 0; mtile < 4; mtile++)
#pragma unroll
        for (int ntl = 0; ntl < 4; ntl++)
          acc[mtile][ntl] = __builtin_amdgcn_mfma_f32_16x16x32_bf16(af[mtile], bf[ntl], acc[mtile][ntl], 0, 0, 0);
    }
    __syncthreads();               // protect buffer before next stage
  }

  // epilogue: D[row=(lane>>4)*4+reg][col=lane&15]
#pragma unroll
  for (int mtile = 0; mtile < 4; mtile++) {
#pragma unroll
    for (int ntl = 0; ntl < 4; ntl++) {
      int ncol = n0 + wn + ntl * 16 + lr;
      float bb = bias[ncol];
#pragma unroll
      for (int r = 0; r < 4; r++) {
        int mrow = wm + mtile * 16 + lq * 4 + r;    // local row 0..127
        float v = acc[mtile][ntl][r] + bb;
        if (MODE == 0) {
          outH[(size_t)(m0 + mrow) * Nd + ncol] = f2bf(gelu_tanh(v));
        } else if (MODE == 2) {
          outH[(size_t)(prow0 + mrow) * Nd + ncol] = f2bf(gelu_tanh(v));
        } else {                                    // MODE 4
          int prow = prow0 + mrow;
          if (e < NE) {
            float w = permw[prow];
            outH[(size_t)prow * Nd + ncol] = f2bf(w * v);      // weighted expert
          } else {
            outF[(size_t)(prow - PERM_CAP) * Nd + ncol] = v;   // shared, f32
          }
        }
      }
    }
  }
}

// distinct names per mode so rocprof shows the per-GEMM breakdown
__global__ __launch_bounds__(256, 4) void gemm_shared_keys(
    const unsigned short* A, const unsigned short* BT, const float* bias,
    const float* bias2, float* outF, unsigned short* outH, int Kd, int Nd,
    const int* perm, const float* permw, const int* tE, const int* tR, const int* nT) {
  gemm_body<0>(A, BT, bias, bias2, outF, outH, Kd, Nd, perm, permw, tE, tR, nT);
}
__global__ __launch_bounds__(256, 4) void gemm_expert_keys(
    const unsigned short* A, const unsigned short* BT, const float* bias,
    const float* bias2, float* outF, unsigned short* outH, int Kd, int Nd,
    const int* perm, const float* permw, const int* tE, const int* tR, const int* nT) {
  gemm_body<2>(A, BT, bias, bias2, outF, outH, Kd, Nd, perm, permw, tE, tR, nT);
}
__global__ __launch_bounds__(256, 4) void gemm_values(
    const unsigned short* A, const unsigned short* BT, const float* bias,
    const float* bias2, float* outF, unsigned short* outH, int Kd, int Nd,
    const int* perm, const float* permw, const int* tE, const int* tR, const int* nT) {
  gemm_body<4>(A, BT, bias, bias2, outF, outH, Kd, Nd, perm, permw, tE, tR, nT);
}

extern "C" void kernel_launch(void* const* d_in, const int* in_sizes, int n_in,
                              void* d_out, int out_size, void* d_ws, size_t ws_size,
                              hipStream_t stream) {
  const float* x        = (const float*)d_in[0];
  const float* gate_w   = (const float*)d_in[1];
  const float* keys_w   = (const float*)d_in[2];
  const float* keys_b   = (const float*)d_in[3];
  const float* values_w = (const float*)d_in[4];
  const float* values_b = (const float*)d_in[5];
  const float* sk_w     = (const float*)d_in[6];
  const float* sk_b     = (const float*)d_in[7];
  const float* sv_w     = (const float*)d_in[8];
  const float* sv_b     = (const float*)d_in[9];
  float* out = (float*)d_out;

  char* p = (char*)d_ws;
  unsigned short* xb   = (unsigned short*)p; p += (size_t)N_TOK * DM * 2;            // 16 MB
  unsigned short* wt   = (unsigned short*)p; p += (size_t)(NE + 1) * DM * HD * 2;    // 75.5 MB (9 slots)
  unsigned short* hid  = (unsigned short*)p; p += (size_t)(PERM_CAP + N_TOK) * HD * 2; // 209.7 MB
  unsigned short* eout = (unsigned short*)p; p += (size_t)PERM_CAP * DM * 2;         // 35.7 MB
  int*   idxb   = (int*)p;   p += NKTOT * 4;
  float* wbuf   = (float*)p; p += NKTOT * 4;
  int*   perm   = (int*)p;   p += PERM_CAP * 4;
  float* permw  = (float*)p; p += PERM_CAP * 4;
  int*   pos    = (int*)p;   p += NKTOT * 4;
  int*   counts = (int*)p;   p += NE * 4;
  int*   fill   = (int*)p;   p += NE * 4;
  int*   poff   = (int*)p;   p += NE * 4;
  float* usage  = (float*)p; p += NE * 4;
  float* zsum   = (float*)p; p += 16;
  int*   tileE  = (int*)p;   p += MAX_TILES * 4;
  int*   tileR  = (int*)p;   p += MAX_TILES * 4;
  int*   nTiles = (int*)p;   p += 16;

  float* lossOut = out + (size_t)N_TOK * DM;
  unsigned short* wt8 = wt + (size_t)NE * DM * HD;          // slot 8 (shared)
  unsigned short* hidS = hid + (size_t)PERM_CAP * HD;       // shared hidden rows

  // 1) init + convert + router
  init_kernel<<<(PERM_CAP + 255) / 256, 256, 0, stream>>>(perm, permw, usage, zsum, counts, fill);
  cvt_x_kernel<<<(N_TOK * DM / 4 + 255) / 256, 256, 0, stream>>>(x, xb);
  router_kernel<<<N_TOK / RTOK_BLK, 256, 0, stream>>>(x, gate_w, idxb, wbuf, usage, zsum, counts);
  scan_kernel<<<1, 64, 0, stream>>>(counts, poff, tileE, tileR, nTiles, usage, zsum, lossOut);
  scatter_kernel<<<NKTOT / 256, 256, 0, stream>>>(idxb, wbuf, poff, fill, perm, permw, pos);

  // 2) keys phase: wt slots 0..7 = keys_w^T, slot 8 = sk_w^T
  transpose_cvt_kernel<<<dim3(DM / 64, HD / 64, NE), 256, 0, stream>>>(keys_w, wt, DM, HD);
  transpose_cvt_kernel<<<dim3(DM / 64, HD / 64, 1), 256, 0, stream>>>(sk_w, wt8, DM, HD);
  gemm_shared_keys<<<2048, 256, 0, stream>>>(             // 2 exact rounds @4/CU
      xb, wt8, sk_b, nullptr, nullptr, hidS, DM, HD, perm, permw, tileE, tileR, nTiles);
  gemm_expert_keys<<<5120, 256, 0, stream>>>(             // 8 xcd * 20(m pad) * 32 n
      xb, wt, keys_b, nullptr, nullptr, hid, DM, HD, perm, permw, tileE, tileR, nTiles);

  // 3) values phase: wt slots 0..7 = values_w^T, slot 8 = sv_w^T; ONE merged GEMM
  transpose_cvt_kernel<<<dim3(HD / 64, DM / 64, NE), 256, 0, stream>>>(values_w, wt, HD, DM);
  transpose_cvt_kernel<<<dim3(HD / 64, DM / 64, 1), 256, 0, stream>>>(sv_w, wt8, HD, DM);
  gemm_values<<<1600, 256, 0, stream>>>(                  // 8 xcd * 25 m * 8 n
      hid, wt, values_b, sv_b, out, eout, HD, DM, perm, permw, tileE, tileR, nTiles);

  // 4) out += top-2 expert contributions
  combine_kernel<<<N_TOK, 128, 0, stream>>>(out, eout, pos);
}